// Round 1
// baseline (177.904 us; speedup 1.0000x reference)
//
#include <hip/hip_runtime.h>

#define NE 32   // electrons
#define NA 8    // atoms
#define DF 4    // dist features
#define KD 8    // kernel dim
#define ED 16   // embedding dim
#define BATCH 4096

__device__ __forceinline__ float sspf(float v) {
    // softplus(v) - ln(2), numerically stable
    float sp = fmaxf(v, 0.0f) + __logf(1.0f + __expf(-fabsf(v)));
    return sp - 0.69314718055994531f;
}

__global__ __launch_bounds__(256) void omni_kernel(
    const float* __restrict__ dists_nuc,   // (B, NE, NA, DF)
    const float* __restrict__ dists_elec,  // (B, NE, NE, DF)
    const float* __restrict__ X,           // (1, ED)
    const float* __restrict__ Y,           // (NA, KD)
    const float* __restrict__ w1,          // (2, DF, 6)
    const float* __restrict__ wb1,         // (2, 6)
    const float* __restrict__ w2,          // (2, 6, KD)
    const float* __restrict__ wb2,         // (2, KD)
    const float* __restrict__ hs_w,        // (2, ED, KD)
    const float* __restrict__ hs_b,        // (2, KD)
    const float* __restrict__ ha_w,        // (2, ED, KD)
    const float* __restrict__ ha_b,        // (2, KD)
    const float* __restrict__ g_w,         // (2, KD, ED)
    const float* __restrict__ g_b,         // (2, ED)
    const float* __restrict__ orb_w,       // (ED,)
    float* __restrict__ out)               // (B,)
{
    const int tid  = threadIdx.x;
    const int wv   = tid >> 6;        // wave in block: 0..3  (one batch elem per wave)
    const int lane = tid & 63;
    const int i    = lane & 31;       // electron index
    const int h    = lane >> 5;       // half: 0 or 1
    const int b    = blockIdx.x * 4 + wv;

    __shared__ float msg[4][2][NE][KD];   // [wave][hs/ha][j][k], 8 KB

    float x[ED];
    #pragma unroll
    for (int c = 0; c < ED; ++c) x[c] = X[c];

    const float* de = dists_elec + (((size_t)b * NE + i) * NE) * DF;
    const float* dn = dists_nuc  + (((size_t)b * NE + i) * NA) * DF;

    const int si = i >> 4;            // spin of electron i

    #pragma unroll 1
    for (int n = 0; n < 2; ++n) {
        // ---- w-subnet weights (uniform -> scalar regs) ----
        float W1[DF][6], B1[6], W2[6][KD], B2[KD];
        {
            const float* p1  = w1  + n * DF * 6;
            const float* pb1 = wb1 + n * 6;
            const float* p2  = w2  + n * 6 * KD;
            const float* pb2 = wb2 + n * KD;
            #pragma unroll
            for (int d = 0; d < DF; ++d)
                #pragma unroll
                for (int a = 0; a < 6; ++a) W1[d][a] = p1[d * 6 + a];
            #pragma unroll
            for (int a = 0; a < 6; ++a) B1[a] = pb1[a];
            #pragma unroll
            for (int a = 0; a < 6; ++a)
                #pragma unroll
                for (int k = 0; k < KD; ++k) W2[a][k] = p2[a * KD + k];
            #pragma unroll
            for (int k = 0; k < KD; ++k) B2[k] = pb2[k];
        }

        // ---- phase 1: message features; half 0 computes hs_i, half 1 computes ha_i ----
        {
            const float* mw = (h == 0 ? hs_w : ha_w) + n * ED * KD;
            const float* mb = (h == 0 ? hs_b : ha_b) + n * KD;
            float mi[KD];
            #pragma unroll
            for (int k = 0; k < KD; ++k) mi[k] = mb[k];
            #pragma unroll
            for (int c = 0; c < ED; ++c) {
                const float xc = x[c];
                #pragma unroll
                for (int k = 0; k < KD; ++k) mi[k] = fmaf(xc, mw[c * KD + k], mi[k]);
            }
            __syncthreads();   // previous-iteration readers done before overwrite
            #pragma unroll
            for (int k = 0; k < KD; ++k) msg[wv][h][i][k] = mi[k];
            __syncthreads();
        }

        float z[KD];
        #pragma unroll
        for (int k = 0; k < KD; ++k) z[k] = 0.0f;

        // ---- electron messages: this half handles j in [16h, 16h+16) (all spin h) ----
        const int t = (h == si) ? 0 : 1;           // same spin -> hs table, else ha
        const float* mrow = &msg[wv][t][0][0];
        #pragma unroll 4
        for (int s = 0; s < 16; ++s) {
            const int j = 16 * h + s;
            const float4 e = *(const float4*)(de + j * DF);
            float act[6];
            #pragma unroll
            for (int a = 0; a < 6; ++a)
                act[a] = sspf(fmaf(e.x, W1[0][a], fmaf(e.y, W1[1][a],
                              fmaf(e.z, W1[2][a], fmaf(e.w, W1[3][a], B1[a])))));
            const float mask = (j == i) ? 0.0f : 1.0f;   // self-exclusion (same-spin only)
            #pragma unroll
            for (int k = 0; k < KD; ++k) {
                float wvk = B2[k];
                #pragma unroll
                for (int a = 0; a < 6; ++a) wvk = fmaf(act[a], W2[a][k], wvk);
                z[k] = fmaf(wvk, mrow[j * KD + k] * mask, z[k]);
            }
        }

        // ---- nuclear messages: this half handles m in [4h, 4h+4) ----
        #pragma unroll
        for (int s = 0; s < 4; ++s) {
            const int m = 4 * h + s;
            const float4 e = *(const float4*)(dn + m * DF);
            float act[6];
            #pragma unroll
            for (int a = 0; a < 6; ++a)
                act[a] = sspf(fmaf(e.x, W1[0][a], fmaf(e.y, W1[1][a],
                              fmaf(e.z, W1[2][a], fmaf(e.w, W1[3][a], B1[a])))));
            #pragma unroll
            for (int k = 0; k < KD; ++k) {
                float wvk = B2[k];
                #pragma unroll
                for (int a = 0; a < 6; ++a) wvk = fmaf(act[a], W2[a][k], wvk);
                z[k] = fmaf(wvk, Y[m * KD + k], z[k]);
            }
        }

        // ---- combine the two halves' partial z ----
        #pragma unroll
        for (int k = 0; k < KD; ++k) z[k] += __shfl_xor(z[k], 32, 64);

        // ---- residual update x += z @ g_w + g_b (duplicated in both halves) ----
        #pragma unroll
        for (int c = 0; c < ED; ++c) {
            float acc = g_b[n * ED + c];
            #pragma unroll
            for (int k = 0; k < KD; ++k)
                acc = fmaf(z[k], g_w[n * KD * ED + k * ED + c], acc);
            x[c] += acc;
        }
    }

    // ---- orbital projection + sum over electrons ----
    float dot = 0.0f;
    #pragma unroll
    for (int c = 0; c < ED; ++c) dot = fmaf(x[c], orb_w[c], dot);
    dot *= 0.5f;   // both halves hold identical x -> 64-lane sum double-counts
    #pragma unroll
    for (int off = 32; off > 0; off >>= 1) dot += __shfl_xor(dot, off, 64);
    if (lane == 0) out[b] = dot;
}

extern "C" void kernel_launch(void* const* d_in, const int* in_sizes, int n_in,
                              void* d_out, int out_size, void* d_ws, size_t ws_size,
                              hipStream_t stream) {
    const float* dists_nuc  = (const float*)d_in[0];
    const float* dists_elec = (const float*)d_in[1];
    const float* X     = (const float*)d_in[2];
    const float* Y     = (const float*)d_in[3];
    const float* w1    = (const float*)d_in[4];
    const float* wb1   = (const float*)d_in[5];
    const float* w2    = (const float*)d_in[6];
    const float* wb2   = (const float*)d_in[7];
    const float* hs_w  = (const float*)d_in[8];
    const float* hs_b  = (const float*)d_in[9];
    const float* ha_w  = (const float*)d_in[10];
    const float* ha_b  = (const float*)d_in[11];
    const float* g_w   = (const float*)d_in[12];
    const float* g_b   = (const float*)d_in[13];
    const float* orb_w = (const float*)d_in[14];
    float* out = (float*)d_out;

    dim3 grid(BATCH / 4), block(256);
    omni_kernel<<<grid, block, 0, stream>>>(dists_nuc, dists_elec, X, Y,
                                            w1, wb1, w2, wb2,
                                            hs_w, hs_b, ha_w, ha_b,
                                            g_w, g_b, orb_w, out);
}